// Round 11
// baseline (86.180 us; speedup 1.0000x reference)
//
#include <hip/hip_runtime.h>
#include <hip/hip_bf16.h>

// Problem constants
constexpr int   kN  = 4096;
constexpr int   kD  = 256;
constexpr float kNU = 3.0f;
constexpr int   kNB = kN / 128;                // 32 block-rows/cols
constexpr int   kNPairs = kNB * (kNB + 1) / 2; // 528 upper-tri block pairs
// Sampled median from diag tile 0, self-pairs excluded
constexpr unsigned kSample0 = 128u * 128u - 128u;        // 16256
constexpr unsigned kTarget0 = (kSample0 - 1u) / 2u + 1u; // lower median rank

using f32x4 = __attribute__((ext_vector_type(4))) float;

// ---------------------------------------------------------------------------
// K1: blocks 1..512: fp32->fp8 + norms/coef (8 rows each).
//     block 0: alpha — self-convert z rows 0..127 to LDS (XOR-16 swizzle),
//     fp8 gram of diag tile 0, LDS hist, median -> alpha_out.
//     (proven in R10: absmax unchanged)
// ---------------------------------------------------------------------------
__global__ __launch_bounds__(256) void prep_kernel(
    const float* __restrict__ z, unsigned int* __restrict__ z8,
    float* __restrict__ norms, float* __restrict__ coef,
    float* __restrict__ alpha_out, unsigned int* __restrict__ done_ctr) {
  __shared__ __align__(16) unsigned char smem[32768];   // fp8 rows 0..127
  __shared__ unsigned int hist[4096];
  __shared__ float nT[128];
  int tid = threadIdx.x;
  int w = tid >> 6, lane = tid & 63;

  if (blockIdx.x != 0) {
    // ---- convert path: 8 rows per block ----
#pragma unroll
    for (int i = 0; i < 2; i++) {
      int row = ((int)blockIdx.x - 1) * 8 + i * 4 + w;
      const float4 v = *(const float4*)(z + (size_t)row * kD + lane * 4);
      unsigned p = 0;
      p = __builtin_amdgcn_cvt_pk_fp8_f32(v.x, v.y, p, false);
      p = __builtin_amdgcn_cvt_pk_fp8_f32(v.z, v.w, p, true);
      z8[((size_t)row * kD >> 2) + lane] = p;
      float sq = v.x * v.x + v.y * v.y + v.z * v.z + v.w * v.w;
      for (int off = 32; off > 0; off >>= 1) sq += __shfl_down(sq, off, 64);
      if (lane == 0) {
        norms[row] = sq;
        coef[row] = -(kNU + (float)kD) / (kNU + sq);   // sigma = 1
      }
    }
    return;
  }

  // ---- alpha path (block 0) ----
  if (tid == 0) __hip_atomic_store(done_ctr, 0u, __ATOMIC_RELAXED,
                                   __HIP_MEMORY_SCOPE_AGENT);
  for (int i = tid; i < 4096; i += 256) hist[i] = 0;
  if (tid < 128) nT[tid] = 0.0f;
  __syncthreads();

#pragma unroll
  for (int i = 0; i < 8; i++) {
    int c = tid + i * 256;
    int row = c >> 4, cc = c & 15;
    const float4* src = (const float4*)(z + (size_t)row * kD + cc * 16);
    float4 v0 = src[0], v1 = src[1], v2 = src[2], v3 = src[3];
    unsigned d[4];
    unsigned p;
    p = 0; p = __builtin_amdgcn_cvt_pk_fp8_f32(v0.x, v0.y, p, false);
    p = __builtin_amdgcn_cvt_pk_fp8_f32(v0.z, v0.w, p, true); d[0] = p;
    p = 0; p = __builtin_amdgcn_cvt_pk_fp8_f32(v1.x, v1.y, p, false);
    p = __builtin_amdgcn_cvt_pk_fp8_f32(v1.z, v1.w, p, true); d[1] = p;
    p = 0; p = __builtin_amdgcn_cvt_pk_fp8_f32(v2.x, v2.y, p, false);
    p = __builtin_amdgcn_cvt_pk_fp8_f32(v2.z, v2.w, p, true); d[2] = p;
    p = 0; p = __builtin_amdgcn_cvt_pk_fp8_f32(v3.x, v3.y, p, false);
    p = __builtin_amdgcn_cvt_pk_fp8_f32(v3.z, v3.w, p, true); d[3] = p;
    int cp = cc ^ (row & 15);
    *(uint4*)(smem + row * 256 + cp * 16) = *(uint4*)d;
    float s = v0.x*v0.x + v0.y*v0.y + v0.z*v0.z + v0.w*v0.w
            + v1.x*v1.x + v1.y*v1.y + v1.z*v1.z + v1.w*v1.w
            + v2.x*v2.x + v2.y*v2.y + v2.z*v2.z + v2.w*v2.w
            + v3.x*v3.x + v3.y*v3.y + v3.z*v3.z + v3.w*v3.w;
    atomicAdd(&nT[row], s);
  }
  __syncthreads();

  int quad = lane >> 4, l15 = lane & 15;
  int waveM = (w >> 1) * 64, waveN = (w & 1) * 64;
  f32x4 acc[4][4] = {};
#pragma unroll
  for (int ks = 0; ks < 8; ks++) {
    int c = ks * 2 + (quad >> 1);
    int intra = (quad & 1) * 8;
    long aL[4], bL[4];
#pragma unroll
    for (int mi = 0; mi < 4; mi++) {
      int row = waveM + mi * 16 + l15;
      aL[mi] = *(const long*)(smem + row * 256 + (c ^ (row & 15)) * 16 + intra);
    }
#pragma unroll
    for (int ni = 0; ni < 4; ni++) {
      int row = waveN + ni * 16 + l15;
      bL[ni] = *(const long*)(smem + row * 256 + (c ^ (row & 15)) * 16 + intra);
    }
#pragma unroll
    for (int mi = 0; mi < 4; mi++)
#pragma unroll
      for (int ni = 0; ni < 4; ni++)
        acc[mi][ni] = __builtin_amdgcn_mfma_f32_16x16x32_fp8_fp8(
            aL[mi], bL[ni], acc[mi][ni], 0, 0, 0);
  }

#pragma unroll
  for (int mi = 0; mi < 4; mi++) {
    int rl0 = waveM + mi * 16 + quad * 4;
#pragma unroll
    for (int r = 0; r < 4; r++) {
      int rl = rl0 + r;
      float ni_ = nT[rl];
#pragma unroll
      for (int nj = 0; nj < 4; nj++) {
        int cl = waveN + nj * 16 + l15;
        if (rl == cl) continue;
        float g = acc[mi][nj][r];
        float dist = fmaxf(ni_ + nT[cl] - 2.0f * g, 0.0f);
        int bin = (int)(dist * 4.0f);
        bin = bin > 4095 ? 4095 : bin;
        atomicAdd(&hist[bin], 1u);
      }
    }
  }
  __syncthreads();

  if (tid < 64) {
    unsigned own = 0;
#pragma unroll
    for (int u = 0; u < 64; u++) own += hist[tid * 64 + u];
    unsigned incl = own;
#pragma unroll
    for (int off = 1; off < 64; off <<= 1) {
      unsigned t = __shfl_up(incl, off, 64);
      if (tid >= off) incl += t;
    }
    unsigned excl = incl - own;
    unsigned long long bal = __ballot(incl >= kTarget0 && excl < kTarget0);
    int chunk = __ffsll((long long)bal) - 1;
    unsigned exclChunk = __shfl(excl, chunk, 64);
    unsigned h = hist[chunk * 64 + tid];
    unsigned fincl = h;
#pragma unroll
    for (int off = 1; off < 64; off <<= 1) {
      unsigned t = __shfl_up(fincl, off, 64);
      if (tid >= off) fincl += t;
    }
    unsigned long long cum = (unsigned long long)exclChunk + (fincl - h);
    if (cum < kTarget0 && cum + h >= kTarget0) {
      int b = chunk * 64 + tid;
      float frac = (float)(kTarget0 - cum) / (float)h;
      float med = ((float)b + frac) * 0.25f;
      alpha_out[0] = 1.0f / (med + 1e-6f);
    }
  }
}

__device__ __forceinline__ void tri_decode(int b, int& by, int& bx) {
  int t = b; by = 0;
  while (t >= kNB - by) { t -= kNB - by; by++; }
  bx = by + t;
}

// ---------------------------------------------------------------------------
// K2: main — R8's proven BK=128 two-volley staged fp8 gram (32 KB LDS,
// 4 blocks/CU) + R8 epilogue; last-block finalize instead of extra dispatch.
// ---------------------------------------------------------------------------
__global__ __launch_bounds__(256, 4) void main_kernel(
    const unsigned char* __restrict__ z8, const float* __restrict__ norms,
    const float* __restrict__ coef, const float* __restrict__ alpha_p,
    unsigned int* done_ctr, double* partials, float* __restrict__ out) {
  __shared__ __align__(16) unsigned char smem[32768];   // A 16 KB | B 16 KB
  __shared__ float nR[128], nC[128], cR[128], cC[128];
  __shared__ double dpart[8];
  __shared__ int sLast;
  unsigned char* ldsA = smem;
  unsigned char* ldsB = smem + 16384;
  int tid = threadIdx.x;
  int lane = tid & 63, w = tid >> 6;

  int by, bx; tri_decode(blockIdx.x, by, bx);
  int bRow = by * 128, bCol = bx * 128;
  if (tid < 128) { nR[tid] = norms[bRow + tid]; cR[tid] = coef[bRow + tid]; }
  else { int u = tid - 128; nC[u] = norms[bCol + u]; cC[u] = coef[bCol + u]; }

  int quad = lane >> 4, l15 = lane & 15;
  int waveM = (w >> 1) * 64, waveN = (w & 1) * 64;

  f32x4 acc[4][4] = {};
  for (int kc = 0; kc < 2; kc++) {
    if (kc) __syncthreads();
#pragma unroll
    for (int s = 0; s < 4; s++) {
      int slot = (w * 4 + s) * 64 + lane;      // 0..1023, 16 B each
      int row = slot >> 3;                     // 8 chunks per 128-B row
      int cp = slot & 7;
      int c = cp ^ (row & 7);
      const unsigned char* gA = z8 + (size_t)(bRow + row) * kD + kc * 128 + c * 16;
      const unsigned char* gB = z8 + (size_t)(bCol + row) * kD + kc * 128 + c * 16;
      __builtin_amdgcn_global_load_lds(
          (const __attribute__((address_space(1))) void*)gA,
          (__attribute__((address_space(3))) void*)(ldsA + (size_t)(w * 4 + s) * 1024),
          16, 0, 0);
      __builtin_amdgcn_global_load_lds(
          (const __attribute__((address_space(1))) void*)gB,
          (__attribute__((address_space(3))) void*)(ldsB + (size_t)(w * 4 + s) * 1024),
          16, 0, 0);
    }
    __syncthreads();
#pragma unroll
    for (int ks = 0; ks < 4; ks++) {           // k = kc*128 + ks*32
      int c = ks * 2 + (quad >> 1);
      int intra = (quad & 1) * 8;
      long aL[4], bL[4];
#pragma unroll
      for (int mi = 0; mi < 4; mi++) {
        int row = waveM + mi * 16 + l15;
        aL[mi] = *(const long*)(ldsA + row * 128 + (c ^ (row & 7)) * 16 + intra);
      }
#pragma unroll
      for (int ni = 0; ni < 4; ni++) {
        int row = waveN + ni * 16 + l15;
        bL[ni] = *(const long*)(ldsB + row * 128 + (c ^ (row & 7)) * 16 + intra);
      }
#pragma unroll
      for (int mi = 0; mi < 4; mi++)
#pragma unroll
        for (int ni = 0; ni < 4; ni++)
          acc[mi][ni] = __builtin_amdgcn_mfma_f32_16x16x32_fp8_fp8(
              aL[mi], bL[ni], acc[mi][ni], 0, 0, 0);
    }
  }

  const float alpha = alpha_p[0];
  const bool diag = (by == bx);
  const float wf = diag ? 1.0f : 2.0f;
  float part = 0.0f;
#pragma unroll
  for (int mi = 0; mi < 4; mi++) {
    int rl0 = waveM + mi * 16 + quad * 4;
#pragma unroll
    for (int r = 0; r < 4; r++) {
      int rl = rl0 + r;
      float ni_ = nR[rl];
      float ci  = cR[rl];
#pragma unroll
      for (int nj = 0; nj < 4; nj++) {
        int cl = waveN + nj * 16 + l15;
        float g = acc[mi][nj][r];
        float njv = nC[cl];
        float cj  = cC[cl];
        float dist = fmaxf(ni_ + njv - 2.0f * g, 0.0f);
        float base = fmaf(alpha, dist, 1.0f);
        float rq  = rsqrtf(base);      // K = base^-0.5
        float rq2 = rq * rq;
        float gc  = -alpha * rq * rq2; // grad_coeff
        float ta  = ci * cj * g * rq;
        float tb  = -gc * ci * (ni_ - g);
        float tc  =  gc * cj * (g - njv);
        float lap =  gc * ((float)kD - 3.0f * alpha * dist * rq2);
        float v = ta + tb + tc + lap;
        if (!(diag && rl == cl)) part += wf * v;
      }
    }
  }

  double d = (double)part;
  for (int off = 32; off > 0; off >>= 1) d += __shfl_down(d, off, 64);
  if (lane == 0) dpart[w] = d;
  __syncthreads();
  if (tid == 0) {
    __hip_atomic_store(&partials[blockIdx.x],
                       dpart[0] + dpart[1] + dpart[2] + dpart[3],
                       __ATOMIC_RELAXED, __HIP_MEMORY_SCOPE_AGENT);
    unsigned old = __hip_atomic_fetch_add(done_ctr, 1u, __ATOMIC_ACQ_REL,
                                          __HIP_MEMORY_SCOPE_AGENT);
    sLast = (old == (unsigned)(kNPairs - 1)) ? 1 : 0;
  }
  __syncthreads();
  if (sLast) {
    double s = 0.0;
    for (int i = tid; i < kNPairs; i += 256)
      s += __hip_atomic_load(&partials[i], __ATOMIC_RELAXED,
                             __HIP_MEMORY_SCOPE_AGENT);
    for (int off = 32; off > 0; off >>= 1) s += __shfl_down(s, off, 64);
    if (lane == 0) dpart[4 + w] = s;
    __syncthreads();
    if (tid == 0) {
      double tot = dpart[4] + dpart[5] + dpart[6] + dpart[7];
      out[0] = (float)(tot / ((double)kN * (double)(kN - 1)));
    }
  }
}

// ---------------------------------------------------------------------------
extern "C" void kernel_launch(void* const* d_in, const int* in_sizes, int n_in,
                              void* d_out, int out_size, void* d_ws, size_t ws_size,
                              hipStream_t stream) {
  const float* z = (const float*)d_in[0];
  float* out = (float*)d_out;

  char* ws = (char*)d_ws;
  unsigned char* z8 = (unsigned char*)ws;                     // 1 MB fp8
  float* norms = (float*)(ws + (size_t)kN * kD);
  float* coef  = norms + kN;
  float* alpha = coef + kN;
  double* partials = (double*)(ws + (2 << 20));               // 8-aligned
  unsigned int* done_ctr = (unsigned int*)(partials + kNPairs);

  prep_kernel<<<kN / 8 + 1, 256, 0, stream>>>(z, (unsigned int*)z8, norms, coef,
                                              alpha, done_ctr);
  main_kernel<<<kNPairs, 256, 0, stream>>>(z8, norms, coef, alpha,
                                           done_ctr, partials, out);
}

// Round 12
// 80.236 us; speedup vs baseline: 1.0741x; 1.0741x over previous
//
#include <hip/hip_runtime.h>
#include <hip/hip_bf16.h>

// Problem constants
constexpr int   kN  = 4096;
constexpr int   kD  = 256;
constexpr float kNU = 3.0f;
constexpr int   kNB = kN / 128;                // 32 block-rows/cols
constexpr int   kNPairs = kNB * (kNB + 1) / 2; // 528 upper-tri block pairs
// Sampled median from diag tile 0, self-pairs excluded
constexpr unsigned kSample0 = 128u * 128u - 128u;        // 16256
constexpr unsigned kTarget0 = (kSample0 - 1u) / 2u + 1u; // lower median rank

using f32x4 = __attribute__((ext_vector_type(4))) float;

// ---------------------------------------------------------------------------
// K1: per-row norms + coeff + fp32 -> fp8(e4m3)   [R8 verbatim]
// ---------------------------------------------------------------------------
__global__ __launch_bounds__(256) void prep_kernel(
    const float* __restrict__ z, unsigned int* __restrict__ z8,
    float* __restrict__ norms, float* __restrict__ coef) {
  int tid = threadIdx.x;
  int w = tid >> 6, lane = tid & 63;
  int row = blockIdx.x * 4 + w;
  const float4 v = *(const float4*)(z + (size_t)row * kD + lane * 4);

  unsigned p = 0;
  p = __builtin_amdgcn_cvt_pk_fp8_f32(v.x, v.y, p, false);  // bytes 0,1
  p = __builtin_amdgcn_cvt_pk_fp8_f32(v.z, v.w, p, true);   // bytes 2,3
  z8[((size_t)row * kD >> 2) + lane] = p;

  float sq = v.x * v.x + v.y * v.y + v.z * v.z + v.w * v.w;
  for (int off = 32; off > 0; off >>= 1) sq += __shfl_down(sq, off, 64);
  if (lane == 0) {
    norms[row] = sq;
    coef[row] = -(kNU + (float)kD) / (kNU + sq);   // sigma = 1
  }
}

// ---------------------------------------------------------------------------
// fp8 gram tile for alpha kernel [R8 verbatim]: BK=128, 2 volleys, syncthreads
// ---------------------------------------------------------------------------
__device__ __forceinline__ void gram_tile_fp8(
    const unsigned char* __restrict__ z8, int bRow, int bCol, int tid,
    unsigned char* ldsA, unsigned char* ldsB, f32x4 acc[4][4]) {
  int lane = tid & 63, w = tid >> 6;
  int quad = lane >> 4, l15 = lane & 15;
  int waveM = (w >> 1) * 64, waveN = (w & 1) * 64;

  for (int kc = 0; kc < 2; kc++) {
    if (kc) __syncthreads();
#pragma unroll
    for (int s = 0; s < 4; s++) {
      int slot = (w * 4 + s) * 64 + lane;      // 0..1023, 16 B each
      int row = slot >> 3;                     // 8 chunks per 128-B row
      int cp = slot & 7;
      int c = cp ^ (row & 7);
      const unsigned char* gA = z8 + (size_t)(bRow + row) * kD + kc * 128 + c * 16;
      const unsigned char* gB = z8 + (size_t)(bCol + row) * kD + kc * 128 + c * 16;
      __builtin_amdgcn_global_load_lds(
          (const __attribute__((address_space(1))) void*)gA,
          (__attribute__((address_space(3))) void*)(ldsA + (size_t)(w * 4 + s) * 1024),
          16, 0, 0);
      __builtin_amdgcn_global_load_lds(
          (const __attribute__((address_space(1))) void*)gB,
          (__attribute__((address_space(3))) void*)(ldsB + (size_t)(w * 4 + s) * 1024),
          16, 0, 0);
    }
    __syncthreads();
#pragma unroll
    for (int ks = 0; ks < 4; ks++) {           // k = kc*128 + ks*32
      int c = ks * 2 + (quad >> 1);
      int intra = (quad & 1) * 8;
      long aL[4], bL[4];
#pragma unroll
      for (int mi = 0; mi < 4; mi++) {
        int row = waveM + mi * 16 + l15;
        aL[mi] = *(const long*)(ldsA + row * 128 + (c ^ (row & 7)) * 16 + intra);
      }
#pragma unroll
      for (int ni = 0; ni < 4; ni++) {
        int row = waveN + ni * 16 + l15;
        bL[ni] = *(const long*)(ldsB + row * 128 + (c ^ (row & 7)) * 16 + intra);
      }
#pragma unroll
      for (int mi = 0; mi < 4; mi++)
#pragma unroll
        for (int ni = 0; ni < 4; ni++)
          acc[mi][ni] = __builtin_amdgcn_mfma_f32_16x16x32_fp8_fp8(
              aL[mi], bL[ni], acc[mi][ni], 0, 0, 0);
    }
  }
}

__device__ __forceinline__ void tri_decode(int b, int& by, int& bx) {
  int t = b; by = 0;
  while (t >= kNB - by) { t -= kNB - by; by++; }
  bx = by + t;
}

// ---------------------------------------------------------------------------
// K2: alpha kernel — ONE block: gram of diag tile 0, LDS hist, median.
// [R8 verbatim]
// ---------------------------------------------------------------------------
__global__ __launch_bounds__(256) void alpha_kernel(
    const unsigned char* __restrict__ z8, const float* __restrict__ norms,
    float* __restrict__ alpha_out) {
  __shared__ __align__(16) unsigned char smem[32768];
  __shared__ unsigned int hist[4096];
  __shared__ float nT[128];
  int tid = threadIdx.x;
  for (int i = tid; i < 4096; i += 256) hist[i] = 0;
  if (tid < 128) nT[tid] = norms[tid];

  int lane = tid & 63, w = tid >> 6;
  int quad = lane >> 4, l15 = lane & 15;
  int waveM = (w >> 1) * 64, waveN = (w & 1) * 64;

  f32x4 acc[4][4] = {};
  gram_tile_fp8(z8, 0, 0, tid, smem, smem + 16384, acc);

#pragma unroll
  for (int mi = 0; mi < 4; mi++) {
    int rl0 = waveM + mi * 16 + quad * 4;
#pragma unroll
    for (int r = 0; r < 4; r++) {
      int rl = rl0 + r;
      float ni_ = nT[rl];
#pragma unroll
      for (int nj = 0; nj < 4; nj++) {
        int cl = waveN + nj * 16 + l15;
        if (rl == cl) continue;
        float g = acc[mi][nj][r];
        float dist = fmaxf(ni_ + nT[cl] - 2.0f * g, 0.0f);
        int bin = (int)(dist * 4.0f);
        bin = bin > 4095 ? 4095 : bin;
        atomicAdd(&hist[bin], 1u);
      }
    }
  }
  __syncthreads();

  if (tid < 64) {
    unsigned own = 0;
#pragma unroll
    for (int u = 0; u < 64; u++) own += hist[tid * 64 + u];
    unsigned incl = own;
#pragma unroll
    for (int off = 1; off < 64; off <<= 1) {
      unsigned t = __shfl_up(incl, off, 64);
      if (tid >= off) incl += t;
    }
    unsigned excl = incl - own;
    unsigned long long bal = __ballot(incl >= kTarget0 && excl < kTarget0);
    int chunk = __ffsll((long long)bal) - 1;
    unsigned exclChunk = __shfl(excl, chunk, 64);
    unsigned h = hist[chunk * 64 + tid];
    unsigned fincl = h;
#pragma unroll
    for (int off = 1; off < 64; off <<= 1) {
      unsigned t = __shfl_up(fincl, off, 64);
      if (tid >= off) fincl += t;
    }
    unsigned long long cum = (unsigned long long)exclChunk + (fincl - h);
    if (cum < kTarget0 && cum + h >= kTarget0) {
      int b = chunk * 64 + tid;
      float frac = (float)(kTarget0 - cum) / (float)h;
      float med = ((float)b + frac) * 0.25f;
      alpha_out[0] = 1.0f / (med + 1e-6f);
    }
  }
}

// ---------------------------------------------------------------------------
// K3: main — dbuf BK=128 pipeline: BOTH volleys issued up front into separate
// 32 KB buffer pairs; first wait is vmcnt(8) (chunk 0 only), chunk 1's drain
// overlaps chunk-0 compute. Raw s_barrier (no compiler vmcnt(0) drain).
// Epilogue scalars direct from global (no ds_write/lgkm hazard).
// 64 KB dynamic LDS -> 2 blocks/CU. Plain partial stores (R8-proven).
// ---------------------------------------------------------------------------
__global__ __launch_bounds__(256, 4) void main_kernel(
    const unsigned char* __restrict__ z8, const float* __restrict__ norms,
    const float* __restrict__ coef, const float* __restrict__ alpha_p,
    double* __restrict__ partials) {
  extern __shared__ __align__(16) unsigned char smem[];  // A0|B0|A1|B1, 16 KB ea
  __shared__ double dpart[4];
  int tid = threadIdx.x;
  int lane = tid & 63, w = tid >> 6;

  int by, bx; tri_decode(blockIdx.x, by, bx);
  int bRow = by * 128, bCol = bx * 128;

  int quad = lane >> 4, l15 = lane & 15;
  int waveM = (w >> 1) * 64, waveN = (w & 1) * 64;

  // ---- issue BOTH chunk volleys up front (16 global_load_lds / thread) ----
#pragma unroll
  for (int kc = 0; kc < 2; kc++) {
    unsigned char* dA = smem + (size_t)kc * 32768;
    unsigned char* dB = dA + 16384;
#pragma unroll
    for (int s = 0; s < 4; s++) {
      int slot = (w * 4 + s) * 64 + lane;      // 0..1023, 16 B each
      int row = slot >> 3;
      int cp = slot & 7;
      int c = cp ^ (row & 7);
      const unsigned char* gA = z8 + (size_t)(bRow + row) * kD + kc * 128 + c * 16;
      const unsigned char* gB = z8 + (size_t)(bCol + row) * kD + kc * 128 + c * 16;
      __builtin_amdgcn_global_load_lds(
          (const __attribute__((address_space(1))) void*)gA,
          (__attribute__((address_space(3))) void*)(dA + (size_t)(w * 4 + s) * 1024),
          16, 0, 0);
      __builtin_amdgcn_global_load_lds(
          (const __attribute__((address_space(1))) void*)gB,
          (__attribute__((address_space(3))) void*)(dB + (size_t)(w * 4 + s) * 1024),
          16, 0, 0);
    }
  }

  f32x4 acc[4][4] = {};
#pragma unroll
  for (int kc = 0; kc < 2; kc++) {
    if (kc == 0) {
      __builtin_amdgcn_s_waitcnt(0x0F78);  // vmcnt(8): chunk 0 landed
    } else {
      __builtin_amdgcn_s_waitcnt(0x0F70);  // vmcnt(0): chunk 1 (overlapped)
    }
    __builtin_amdgcn_s_barrier();          // raw barrier — no forced drain
    const unsigned char* ldsA = smem + (size_t)kc * 32768;
    const unsigned char* ldsB = ldsA + 16384;
#pragma unroll
    for (int ks = 0; ks < 4; ks++) {       // k = kc*128 + ks*32
      int c = ks * 2 + (quad >> 1);
      int intra = (quad & 1) * 8;
      long aL[4], bL[4];
#pragma unroll
      for (int mi = 0; mi < 4; mi++) {
        int row = waveM + mi * 16 + l15;
        aL[mi] = *(const long*)(ldsA + row * 128 + (c ^ (row & 7)) * 16 + intra);
      }
#pragma unroll
      for (int ni = 0; ni < 4; ni++) {
        int row = waveN + ni * 16 + l15;
        bL[ni] = *(const long*)(ldsB + row * 128 + (c ^ (row & 7)) * 16 + intra);
      }
#pragma unroll
      for (int mi = 0; mi < 4; mi++)
#pragma unroll
        for (int ni = 0; ni < 4; ni++)
          acc[mi][ni] = __builtin_amdgcn_mfma_f32_16x16x32_fp8_fp8(
              aL[mi], bL[ni], acc[mi][ni], 0, 0, 0);
    }
  }

  // ---- epilogue: scalars direct from global (L2-hot 16 KB tables) ----
  const float alpha = alpha_p[0];
  const bool diag = (by == bx);
  const float wf = diag ? 1.0f : 2.0f;
  float njv[4], cjv[4];
#pragma unroll
  for (int nj = 0; nj < 4; nj++) {
    int cg = bCol + waveN + nj * 16 + l15;
    njv[nj] = norms[cg];
    cjv[nj] = coef[cg];
  }
  float part = 0.0f;
#pragma unroll
  for (int mi = 0; mi < 4; mi++) {
    int rl0 = waveM + mi * 16 + quad * 4;
#pragma unroll
    for (int r = 0; r < 4; r++) {
      int rl = rl0 + r;
      float ni_ = norms[bRow + rl];        // wave-uniform -> scalar path
      float ci  = coef[bRow + rl];
#pragma unroll
      for (int nj = 0; nj < 4; nj++) {
        int cl = waveN + nj * 16 + l15;
        float g = acc[mi][nj][r];
        float dist = fmaxf(ni_ + njv[nj] - 2.0f * g, 0.0f);
        float base = fmaf(alpha, dist, 1.0f);
        float rq  = rsqrtf(base);          // K = base^-0.5
        float rq2 = rq * rq;
        float gc  = -alpha * rq * rq2;     // grad_coeff
        float ta  = ci * cjv[nj] * g * rq;
        float tb  = -gc * ci * (ni_ - g);
        float tc  =  gc * cjv[nj] * (g - njv[nj]);
        float lap =  gc * ((float)kD - 3.0f * alpha * dist * rq2);
        float v = ta + tb + tc + lap;
        if (!(diag && rl == cl)) part += wf * v;
      }
    }
  }

  double d = (double)part;
  for (int off = 32; off > 0; off >>= 1) d += __shfl_down(d, off, 64);
  if (lane == 0) dpart[w] = d;
  __syncthreads();
  if (tid == 0) partials[blockIdx.x] = dpart[0] + dpart[1] + dpart[2] + dpart[3];
}

// ---------------------------------------------------------------------------
// K4: finalize — one block sums 528 partials  [R8 verbatim]
// ---------------------------------------------------------------------------
__global__ __launch_bounds__(256) void finalize_kernel(
    const double* __restrict__ partials, float* __restrict__ out) {
  __shared__ double dpart[4];
  int tid = threadIdx.x;
  int lane = tid & 63, w = tid >> 6;
  double s = 0.0;
  for (int i = tid; i < kNPairs; i += 256) s += partials[i];
  for (int off = 32; off > 0; off >>= 1) s += __shfl_down(s, off, 64);
  if (lane == 0) dpart[w] = s;
  __syncthreads();
  if (tid == 0) {
    double tot = dpart[0] + dpart[1] + dpart[2] + dpart[3];
    out[0] = (float)(tot / ((double)kN * (double)(kN - 1)));
  }
}

// ---------------------------------------------------------------------------
extern "C" void kernel_launch(void* const* d_in, const int* in_sizes, int n_in,
                              void* d_out, int out_size, void* d_ws, size_t ws_size,
                              hipStream_t stream) {
  const float* z = (const float*)d_in[0];
  float* out = (float*)d_out;

  char* ws = (char*)d_ws;
  unsigned char* z8 = (unsigned char*)ws;                     // 1 MB fp8
  float* norms = (float*)(ws + (size_t)kN * kD);
  float* coef  = norms + kN;
  float* alpha = coef + kN;
  double* partials = (double*)(ws + (2 << 20));               // 8-aligned

  prep_kernel<<<kN / 4, 256, 0, stream>>>(z, (unsigned int*)z8, norms, coef);
  alpha_kernel<<<1, 256, 0, stream>>>(z8, norms, alpha);
  main_kernel<<<kNPairs, 256, 65536, stream>>>(z8, norms, coef, alpha, partials);
  finalize_kernel<<<1, 256, 0, stream>>>(partials, out);
}